// Round 1
// baseline (658.263 us; speedup 1.0000x reference)
//
#include <hip/hip_runtime.h>
#include <math.h>

#define BB 2
#define DD 128
#define HH 256
#define WW 256
#define KK 4
#define HWC (HH*WW)

// ---------------- Kernel 1: 3x3 convs -> offsets(8) + softmaxed attn(4) ----------------
// block = one output row (b,i), thread j. Output layout ws: [b][12][H][W]
__global__ __launch_bounds__(256) void k1_convs(
    const float* __restrict__ bev, const float* __restrict__ offw,
    const float* __restrict__ offb, const float* __restrict__ wtw,
    const float* __restrict__ wtb, float* __restrict__ oa)
{
    __shared__ float wlds[128*108]; // [c][o(12)][t(9)]
    int tid = threadIdx.x;
    for (int idx = tid; idx < 128*108; idx += 256) {
        int c = idx / 108; int r = idx % 108; int o = r / 9; int t = r % 9;
        float v = (o < 8) ? offw[(o*128 + c)*9 + t] : wtw[((o-8)*128 + c)*9 + t];
        wlds[idx] = v;
    }
    __syncthreads();

    int p = blockIdx.x;          // 0 .. B*H-1
    int b = p / HH; int i = p % HH; int j = tid;
    float acc[12];
    #pragma unroll
    for (int o = 0; o < 12; o++) acc[o] = 0.f;

    const float* bb = bev + (size_t)b * DD * HWC;
    for (int c = 0; c < 128; c++) {
        const float* pl = bb + c * HWC;
        float v[9];
        #pragma unroll
        for (int dy = 0; dy < 3; dy++) {
            int y = i + dy - 1;
            bool yok = ((unsigned)y < HH);
            #pragma unroll
            for (int dx = 0; dx < 3; dx++) {
                int x = j + dx - 1;
                bool ok = yok && ((unsigned)x < WW);
                v[dy*3 + dx] = ok ? pl[y*WW + x] : 0.f;
            }
        }
        const float* wl = &wlds[c*108];
        #pragma unroll
        for (int o = 0; o < 12; o++) {
            float s = acc[o];
            #pragma unroll
            for (int t = 0; t < 9; t++) s = fmaf(wl[o*9 + t], v[t], s);
            acc[o] = s;
        }
    }

    float outv[12];
    #pragma unroll
    for (int o = 0; o < 8; o++) outv[o] = acc[o] + offb[o];   // OFFSET_SCALE = 1.0
    float l[4];
    #pragma unroll
    for (int k = 0; k < 4; k++) l[k] = acc[8+k] + wtb[k];
    float m = fmaxf(fmaxf(l[0], l[1]), fmaxf(l[2], l[3]));
    float e[4]; float se = 0.f;
    #pragma unroll
    for (int k = 0; k < 4; k++) { e[k] = expf(l[k] - m); se += e[k]; }
    float inv = 1.f / se;
    #pragma unroll
    for (int k = 0; k < 4; k++) outv[8+k] = e[k] * inv;

    size_t basep = (size_t)b * 12 * HWC + (size_t)i * WW + j;
    #pragma unroll
    for (int o = 0; o < 12; o++) oa[basep + (size_t)o * HWC] = outv[o];
}

// ---------------- Kernel 2: deformable sample + K-aggregate + 1x1 proj ----------------
// Transpose quirk of the reference: output (i,j) samples bev at (row ~ j+dy, col ~ i+dx).
// Map lane<->i so gather addresses are consecutive along width (coalesced).
// block = one output column (b,j), thread i. Writes pre-BN y into d_out (natural layout).
__global__ __launch_bounds__(256, 2) void k2_sample_proj(
    const float* __restrict__ bev, const float* __restrict__ oa,
    const float* __restrict__ projw, float* __restrict__ y)
{
    __shared__ float projT[128*128];   // [d][o]
    int tid = threadIdx.x;
    for (int idx = tid; idx < 128*128; idx += 256) {
        int d = idx >> 7; int o = idx & 127;
        projT[idx] = projw[o*128 + d];
    }
    __syncthreads();

    int b = blockIdx.x / WW; int j = blockIdx.x % WW; int i = tid;
    const float* ob = oa + (size_t)b * 12 * HWC + (size_t)i * WW + j;

    int addr[16]; float cw[16];
    #pragma unroll
    for (int k = 0; k < 4; k++) {
        float dx = ob[(size_t)(2*k)   * HWC];
        float dy = ob[(size_t)(2*k+1) * HWC];
        float a  = ob[(size_t)(8+k)   * HWC];
        float x  = fminf(fmaxf((float)i + dx, 0.f), (float)(WW-1));
        float yy = fminf(fmaxf((float)j + dy, 0.f), (float)(HH-1));
        float x0f = floorf(x); float y0f = floorf(yy);
        int x0 = (int)x0f; int y0 = (int)y0f;
        int x1 = min(x0 + 1, WW - 1); int y1 = min(y0 + 1, HH - 1);
        float wx = x - x0f; float wy = yy - y0f;
        addr[k*4+0] = y0*WW + x0; cw[k*4+0] = a * (1.f - wx) * (1.f - wy);
        addr[k*4+1] = y0*WW + x1; cw[k*4+1] = a * wx * (1.f - wy);
        addr[k*4+2] = y1*WW + x0; cw[k*4+2] = a * (1.f - wx) * wy;
        addr[k*4+3] = y1*WW + x1; cw[k*4+3] = a * wx * wy;
    }

    const float* bb = bev + (size_t)b * DD * HWC;
    float acc[128];
    #pragma unroll
    for (int o = 0; o < 128; o++) acc[o] = 0.f;

    for (int d = 0; d < 128; d++) {
        const float* pl = bb + d * HWC;
        float s = 0.f;
        #pragma unroll
        for (int t = 0; t < 16; t++) s = fmaf(cw[t], pl[addr[t]], s);
        const float4* pr = (const float4*)&projT[d << 7];
        #pragma unroll
        for (int o4 = 0; o4 < 32; o4++) {
            float4 wv = pr[o4];
            acc[o4*4+0] = fmaf(wv.x, s, acc[o4*4+0]);
            acc[o4*4+1] = fmaf(wv.y, s, acc[o4*4+1]);
            acc[o4*4+2] = fmaf(wv.z, s, acc[o4*4+2]);
            acc[o4*4+3] = fmaf(wv.w, s, acc[o4*4+3]);
        }
    }

    size_t basep = (size_t)b * DD * HWC + (size_t)i * WW + j;
    #pragma unroll
    for (int o = 0; o < 128; o++) y[basep + (size_t)o * HWC] = acc[o];
}

// ---------------- Kernel 3: per-channel BN stats (deterministic, no atomics) ----------------
__global__ __launch_bounds__(256) void k3_stats(
    const float* __restrict__ y, const float* __restrict__ gamma,
    const float* __restrict__ beta, float* __restrict__ stats)
{
    int o = blockIdx.x; int tid = threadIdx.x;
    double s = 0.0, s2 = 0.0;
    for (int b = 0; b < BB; b++) {
        const float* pl = y + ((size_t)b * DD + o) * HWC;
        for (int idx = tid; idx < HWC; idx += 256) {
            float v = pl[idx];
            s += v; s2 += (double)v * v;
        }
    }
    __shared__ double ls[256], ls2[256];
    ls[tid] = s; ls2[tid] = s2;
    __syncthreads();
    for (int off = 128; off > 0; off >>= 1) {
        if (tid < off) { ls[tid] += ls[tid+off]; ls2[tid] += ls2[tid+off]; }
        __syncthreads();
    }
    if (tid == 0) {
        double N = (double)(BB * HWC);
        double mean = ls[0] / N;
        double var = ls2[0] / N - mean * mean;
        double invs = 1.0 / sqrt(var + 1e-5);
        double g = (double)gamma[o];
        stats[o*2]   = (float)(g * invs);
        stats[o*2+1] = (float)((double)beta[o] - mean * g * invs);
    }
}

// ---------------- Kernel 4: BN + exact GELU, in-place on d_out ----------------
__global__ __launch_bounds__(256) void k4_bn_gelu(
    float* __restrict__ y, const float* __restrict__ stats)
{
    size_t idx4 = (size_t)blockIdx.x * 256 + threadIdx.x;  // float4 index
    float4* p = (float4*)y;
    float4 v = p[idx4];
    int o = (int)((idx4 * 4) / HWC) % DD;
    float sc = stats[o*2], sh = stats[o*2+1];
    const float inv_sqrt2 = 0.70710678118654752f;
    float g0 = fmaf(v.x, sc, sh);
    float g1 = fmaf(v.y, sc, sh);
    float g2 = fmaf(v.z, sc, sh);
    float g3 = fmaf(v.w, sc, sh);
    v.x = 0.5f * g0 * (1.f + erff(g0 * inv_sqrt2));
    v.y = 0.5f * g1 * (1.f + erff(g1 * inv_sqrt2));
    v.z = 0.5f * g2 * (1.f + erff(g2 * inv_sqrt2));
    v.w = 0.5f * g3 * (1.f + erff(g3 * inv_sqrt2));
    p[idx4] = v;
}

extern "C" void kernel_launch(void* const* d_in, const int* in_sizes, int n_in,
                              void* d_out, int out_size, void* d_ws, size_t ws_size,
                              hipStream_t stream) {
    const float* bev   = (const float*)d_in[0];
    const float* offw  = (const float*)d_in[1];
    const float* offb  = (const float*)d_in[2];
    const float* wtw   = (const float*)d_in[3];
    const float* wtb   = (const float*)d_in[4];
    const float* projw = (const float*)d_in[5];
    const float* gamma = (const float*)d_in[6];
    const float* beta  = (const float*)d_in[7];
    float* out = (float*)d_out;

    float* oa    = (float*)d_ws;                       // B*12*H*W floats = 6.3 MB
    float* stats = oa + (size_t)BB * 12 * HWC;         // 256 floats

    hipLaunchKernelGGL(k1_convs, dim3(BB*HH), dim3(256), 0, stream,
                       bev, offw, offb, wtw, wtb, oa);
    hipLaunchKernelGGL(k2_sample_proj, dim3(BB*WW), dim3(256), 0, stream,
                       bev, oa, projw, out);
    hipLaunchKernelGGL(k3_stats, dim3(DD), dim3(256), 0, stream,
                       out, gamma, beta, stats);
    hipLaunchKernelGGL(k4_bn_gelu, dim3((BB*DD*HWC)/1024), dim3(256), 0, stream,
                       out, stats);
}

// Round 2
// 534.570 us; speedup vs baseline: 1.2314x; 1.2314x over previous
//
#include <hip/hip_runtime.h>
#include <math.h>

#define BB 2
#define DD 128
#define HH 256
#define WW 256
#define KK 4
#define HWC (HH*WW)

// ---------------- Kernel 0: transpose proj weights [o][d] -> WT[d][o] ----------------
__global__ __launch_bounds__(256) void k0_transpose(
    const float* __restrict__ projw, float* __restrict__ wt)
{
    int idx = blockIdx.x * 256 + threadIdx.x;   // 16384 total
    int d = idx >> 7, o = idx & 127;
    wt[d * 128 + o] = projw[o * 128 + d];
}

// ---------------- Kernel 1: 3x3 convs -> offsets(8) + softmaxed attn(4) ----------------
// block = one output row (b,i), thread j. Output layout ws: [b][12][H][W]
__global__ __launch_bounds__(256) void k1_convs(
    const float* __restrict__ bev, const float* __restrict__ offw,
    const float* __restrict__ offb, const float* __restrict__ wtw,
    const float* __restrict__ wtb, float* __restrict__ oa)
{
    __shared__ float wlds[128*108]; // [c][o(12)][t(9)]
    int tid = threadIdx.x;
    for (int idx = tid; idx < 128*108; idx += 256) {
        int c = idx / 108; int r = idx % 108; int o = r / 9; int t = r % 9;
        float v = (o < 8) ? offw[(o*128 + c)*9 + t] : wtw[((o-8)*128 + c)*9 + t];
        wlds[idx] = v;
    }
    __syncthreads();

    int p = blockIdx.x;          // 0 .. B*H-1
    int b = p / HH; int i = p % HH; int j = tid;
    float acc[12];
    #pragma unroll
    for (int o = 0; o < 12; o++) acc[o] = 0.f;

    const float* bb = bev + (size_t)b * DD * HWC;
    for (int c = 0; c < 128; c++) {
        const float* pl = bb + c * HWC;
        float v[9];
        #pragma unroll
        for (int dy = 0; dy < 3; dy++) {
            int y = i + dy - 1;
            bool yok = ((unsigned)y < HH);
            #pragma unroll
            for (int dx = 0; dx < 3; dx++) {
                int x = j + dx - 1;
                bool ok = yok && ((unsigned)x < WW);
                v[dy*3 + dx] = ok ? pl[y*WW + x] : 0.f;
            }
        }
        const float* wl = &wlds[c*108];
        #pragma unroll
        for (int o = 0; o < 12; o++) {
            float s = acc[o];
            #pragma unroll
            for (int t = 0; t < 9; t++) s = fmaf(wl[o*9 + t], v[t], s);
            acc[o] = s;
        }
    }

    float outv[12];
    #pragma unroll
    for (int o = 0; o < 8; o++) outv[o] = acc[o] + offb[o];   // OFFSET_SCALE = 1.0
    float l[4];
    #pragma unroll
    for (int k = 0; k < 4; k++) l[k] = acc[8+k] + wtb[k];
    float m = fmaxf(fmaxf(l[0], l[1]), fmaxf(l[2], l[3]));
    float e[4]; float se = 0.f;
    #pragma unroll
    for (int k = 0; k < 4; k++) { e[k] = expf(l[k] - m); se += e[k]; }
    float inv = 1.f / se;
    #pragma unroll
    for (int k = 0; k < 4; k++) outv[8+k] = e[k] * inv;

    size_t basep = (size_t)b * 12 * HWC + (size_t)i * WW + j;
    #pragma unroll
    for (int o = 0; o < 12; o++) oa[basep + (size_t)o * HWC] = outv[o];
}

// ---------------- Kernel 2: deformable sample + K-aggregate + 1x1 proj ----------------
// Transpose quirk: output (p,q) [p=h idx, q=w idx] samples bev at (row ~ q+dy, col ~ p+dx).
// Block = 16x16 pixel tile, 512 threads.
// Gather phase: lanes p-fast -> coalesced gathers; per-d sampled value staged in LDS S.
// GEMM phase: 8 waves x 16 output channels; lane owns 16 o x 4 consecutive-q pixels ->
// fully-coalesced float4 stores (fixes the 10x write amplification of round 1).
__global__ __launch_bounds__(512, 2) void k2_sample_proj(
    const float* __restrict__ bev, const float* __restrict__ oa,
    const float* __restrict__ wt, float* __restrict__ y)
{
    __shared__ float S[16][256];    // [d-local][swizzled pix]   16 KB
    __shared__ float WT[16][128];   // [d-local][o]               8 KB

    int tid = threadIdx.x;
    int bidx = blockIdx.x;
    int b  = bidx >> 8;
    int tp = (bidx >> 4) & 15;
    int tq = bidx & 15;
    int p0 = tp * 16, q0 = tq * 16;

    // ---- gather-phase identity: pixel index p-fast ----
    int pix = tid & 255;
    int gq = pix >> 4;        // local q (w index)
    int gp = pix & 15;        // local p (h index)
    int dgrp = tid >> 8;      // 0/1: which 8-d half of the 16-d chunk
    int swpix = gq * 16 + ((gp + gq) & 15);   // swizzled S column

    // ---- offsets / attention for this pixel ----
    const float* ob = oa + (size_t)b * 12 * HWC + (size_t)(p0 + gp) * WW + (q0 + gq);
    int addr[16]; float cw[16];
    #pragma unroll
    for (int k = 0; k < 4; k++) {
        float dx = ob[(size_t)(2*k)   * HWC];
        float dy = ob[(size_t)(2*k+1) * HWC];
        float a  = ob[(size_t)(8+k)   * HWC];
        float x  = fminf(fmaxf((float)(p0 + gp) + dx, 0.f), (float)(WW-1));
        float yy = fminf(fmaxf((float)(q0 + gq) + dy, 0.f), (float)(HH-1));
        float x0f = floorf(x); float y0f = floorf(yy);
        int x0 = (int)x0f; int y0 = (int)y0f;
        int x1 = min(x0 + 1, WW - 1); int y1 = min(y0 + 1, HH - 1);
        float wx = x - x0f; float wy = yy - y0f;
        addr[k*4+0] = y0*WW + x0; cw[k*4+0] = a * (1.f - wx) * (1.f - wy);
        addr[k*4+1] = y0*WW + x1; cw[k*4+1] = a * wx * (1.f - wy);
        addr[k*4+2] = y1*WW + x0; cw[k*4+2] = a * (1.f - wx) * wy;
        addr[k*4+3] = y1*WW + x1; cw[k*4+3] = a * wx * wy;
    }

    // ---- GEMM-phase identity ----
    int wv   = tid >> 6;           // wave 0..7 -> o in [16*wv, 16*wv+16)
    int lane = tid & 63;
    int lp   = lane >> 2;          // local p (h) 0..15
    int lq0  = (lane & 3) << 2;    // local q (w) base: 0,4,8,12
    int spix[4];
    #pragma unroll
    for (int t = 0; t < 4; t++) {
        int qq = lq0 + t;
        spix[t] = qq * 16 + ((lp + qq) & 15);
    }

    float acc[64];
    #pragma unroll
    for (int t = 0; t < 64; t++) acc[t] = 0.f;

    const float* bb = bev + (size_t)b * DD * HWC;

    for (int d0 = 0; d0 < 128; d0 += 16) {
        // gather: 8 d per thread
        #pragma unroll 2
        for (int dd = 0; dd < 8; dd++) {
            int dl = dgrp * 8 + dd;
            const float* pl = bb + (size_t)(d0 + dl) * HWC;
            float s = 0.f;
            #pragma unroll
            for (int t = 0; t < 16; t++) s = fmaf(cw[t], pl[addr[t]], s);
            S[dl][swpix] = s;
        }
        // stage WT chunk: 2048 floats -> one float4 per thread (coalesced)
        {
            int dl = tid >> 5; int o4 = tid & 31;
            ((float4*)&WT[dl][0])[o4] = ((const float4*)(wt + (size_t)(d0 + dl) * 128))[o4];
        }
        __syncthreads();

        // GEMM: per d, 4 broadcast float4 W-reads + 4 swizzled S-reads + 64 FMA
        #pragma unroll
        for (int dl = 0; dl < 16; dl++) {
            float sv[4];
            #pragma unroll
            for (int t = 0; t < 4; t++) sv[t] = S[dl][spix[t]];
            const float4* wrow = (const float4*)&WT[dl][wv * 16];
            #pragma unroll
            for (int oi4 = 0; oi4 < 4; oi4++) {
                float4 wvv = wrow[oi4];
                int ob4 = oi4 * 16;
                acc[ob4+ 0] = fmaf(wvv.x, sv[0], acc[ob4+ 0]);
                acc[ob4+ 1] = fmaf(wvv.x, sv[1], acc[ob4+ 1]);
                acc[ob4+ 2] = fmaf(wvv.x, sv[2], acc[ob4+ 2]);
                acc[ob4+ 3] = fmaf(wvv.x, sv[3], acc[ob4+ 3]);
                acc[ob4+ 4] = fmaf(wvv.y, sv[0], acc[ob4+ 4]);
                acc[ob4+ 5] = fmaf(wvv.y, sv[1], acc[ob4+ 5]);
                acc[ob4+ 6] = fmaf(wvv.y, sv[2], acc[ob4+ 6]);
                acc[ob4+ 7] = fmaf(wvv.y, sv[3], acc[ob4+ 7]);
                acc[ob4+ 8] = fmaf(wvv.z, sv[0], acc[ob4+ 8]);
                acc[ob4+ 9] = fmaf(wvv.z, sv[1], acc[ob4+ 9]);
                acc[ob4+10] = fmaf(wvv.z, sv[2], acc[ob4+10]);
                acc[ob4+11] = fmaf(wvv.z, sv[3], acc[ob4+11]);
                acc[ob4+12] = fmaf(wvv.w, sv[0], acc[ob4+12]);
                acc[ob4+13] = fmaf(wvv.w, sv[1], acc[ob4+13]);
                acc[ob4+14] = fmaf(wvv.w, sv[2], acc[ob4+14]);
                acc[ob4+15] = fmaf(wvv.w, sv[3], acc[ob4+15]);
            }
        }
        __syncthreads();
    }

    // coalesced float4 stores: lanes 0-3 cover one full 64B line
    size_t base = (size_t)b * DD * HWC + (size_t)(p0 + lp) * WW + (q0 + lq0);
    #pragma unroll
    for (int oi = 0; oi < 16; oi++) {
        int o = wv * 16 + oi;
        float4 v = make_float4(acc[oi*4+0], acc[oi*4+1], acc[oi*4+2], acc[oi*4+3]);
        *(float4*)(y + base + (size_t)o * HWC) = v;
    }
}

// ---------------- Kernel 3: per-channel BN stats (deterministic, no atomics) ----------------
__global__ __launch_bounds__(256) void k3_stats(
    const float* __restrict__ y, const float* __restrict__ gamma,
    const float* __restrict__ beta, float* __restrict__ stats)
{
    int o = blockIdx.x; int tid = threadIdx.x;
    double s = 0.0, s2 = 0.0;
    for (int b = 0; b < BB; b++) {
        const float* pl = y + ((size_t)b * DD + o) * HWC;
        for (int idx = tid; idx < HWC; idx += 256) {
            float v = pl[idx];
            s += v; s2 += (double)v * v;
        }
    }
    __shared__ double ls[256], ls2[256];
    ls[tid] = s; ls2[tid] = s2;
    __syncthreads();
    for (int off = 128; off > 0; off >>= 1) {
        if (tid < off) { ls[tid] += ls[tid+off]; ls2[tid] += ls2[tid+off]; }
        __syncthreads();
    }
    if (tid == 0) {
        double N = (double)(BB * HWC);
        double mean = ls[0] / N;
        double var = ls2[0] / N - mean * mean;
        double invs = 1.0 / sqrt(var + 1e-5);
        double g = (double)gamma[o];
        stats[o*2]   = (float)(g * invs);
        stats[o*2+1] = (float)((double)beta[o] - mean * g * invs);
    }
}

// ---------------- Kernel 4: BN + exact GELU, in-place on d_out ----------------
__global__ __launch_bounds__(256) void k4_bn_gelu(
    float* __restrict__ y, const float* __restrict__ stats)
{
    size_t idx4 = (size_t)blockIdx.x * 256 + threadIdx.x;  // float4 index
    float4* p = (float4*)y;
    float4 v = p[idx4];
    int o = (int)((idx4 * 4) / HWC) % DD;
    float sc = stats[o*2], sh = stats[o*2+1];
    const float inv_sqrt2 = 0.70710678118654752f;
    float g0 = fmaf(v.x, sc, sh);
    float g1 = fmaf(v.y, sc, sh);
    float g2 = fmaf(v.z, sc, sh);
    float g3 = fmaf(v.w, sc, sh);
    v.x = 0.5f * g0 * (1.f + erff(g0 * inv_sqrt2));
    v.y = 0.5f * g1 * (1.f + erff(g1 * inv_sqrt2));
    v.z = 0.5f * g2 * (1.f + erff(g2 * inv_sqrt2));
    v.w = 0.5f * g3 * (1.f + erff(g3 * inv_sqrt2));
    p[idx4] = v;
}

extern "C" void kernel_launch(void* const* d_in, const int* in_sizes, int n_in,
                              void* d_out, int out_size, void* d_ws, size_t ws_size,
                              hipStream_t stream) {
    const float* bev   = (const float*)d_in[0];
    const float* offw  = (const float*)d_in[1];
    const float* offb  = (const float*)d_in[2];
    const float* wtw   = (const float*)d_in[3];
    const float* wtb   = (const float*)d_in[4];
    const float* projw = (const float*)d_in[5];
    const float* gamma = (const float*)d_in[6];
    const float* beta  = (const float*)d_in[7];
    float* out = (float*)d_out;

    float* oa    = (float*)d_ws;                        // B*12*H*W floats = 6.3 MB
    float* wtT   = oa + (size_t)BB * 12 * HWC;          // 128*128 floats = 64 KB
    float* stats = wtT + 128 * 128;                     // 256 floats

    hipLaunchKernelGGL(k0_transpose, dim3(64), dim3(256), 0, stream,
                       projw, wtT);
    hipLaunchKernelGGL(k1_convs, dim3(BB*HH), dim3(256), 0, stream,
                       bev, offw, offb, wtw, wtb, oa);
    hipLaunchKernelGGL(k2_sample_proj, dim3(BB*256), dim3(512), 0, stream,
                       bev, oa, wtT, out);
    hipLaunchKernelGGL(k3_stats, dim3(DD), dim3(256), 0, stream,
                       out, gamma, beta, stats);
    hipLaunchKernelGGL(k4_bn_gelu, dim3((BB*DD*HWC)/1024), dim3(256), 0, stream,
                       out, stats);
}